// Round 16
// baseline (239.656 us; speedup 1.0000x reference)
//
#include <hip/hip_runtime.h>

#define B_ 4
#define H_ 16
#define SQ 1024
#define SK 1024
#define DHD 64
#define E_ 1024

typedef _Float16 half_t;
typedef __attribute__((ext_vector_type(8))) _Float16 half8;
typedef __attribute__((ext_vector_type(4))) _Float16 half4;
typedef __attribute__((ext_vector_type(4))) float f32x4;

static __device__ __forceinline__ f32x4 mfma16h(half8 a, half8 b, f32x4 c) {
  return __builtin_amdgcn_mfma_f32_16x16x32_f16(a, b, c, 0, 0, 0);
}
// LDS-only barrier: does NOT drain vmcnt (async strip loads stay in flight;
// __syncthreads would emit s_waitcnt vmcnt(0) and kill the pipeline)
static __device__ __forceinline__ void lds_barrier() {
  asm volatile("s_waitcnt lgkmcnt(0)" ::: "memory");
  __builtin_amdgcn_s_barrier();
}

// ---- fused prep: emb/Wq fp32->fp16, K -> -K fp16, V -> V^T fp16 ----
#define QW_BLOCKS 2560  // 2048 (emb) + 512 (wq)
__global__ __launch_bounds__(256) void prep_kernel(const float* __restrict__ emb,
                                                   const float* __restrict__ wq,
                                                   const float* __restrict__ K,
                                                   const float* __restrict__ V,
                                                   half_t* __restrict__ emb_h,
                                                   half_t* __restrict__ wq_h,
                                                   half_t* __restrict__ khn,
                                                   half_t* __restrict__ vt) {
  int bid = blockIdx.x, tid = threadIdx.x;
  if (bid < QW_BLOCKS) {
    int i = bid * 256 + tid;
    const float* src;
    half_t* dst;
    if (i < (B_ * SQ * E_ / 8)) {
      src = emb;
      dst = emb_h;
    } else {
      i -= B_ * SQ * E_ / 8;
      src = wq;
      dst = wq_h;
    }
    size_t off = (size_t)i * 8;
    f32x4 v0 = *(const f32x4*)(src + off);
    f32x4 v1 = *(const f32x4*)(src + off + 4);
    half8 h;
#pragma unroll
    for (int j = 0; j < 4; ++j) {
      h[j] = (half_t)v0[j];
      h[4 + j] = (half_t)v1[j];
    }
    *(half8*)(dst + off) = h;
    return;
  }
  bid -= QW_BLOCKS;  // 1024 kv blocks
  int bh = bid >> 4, kt = bid & 15;
  const float* ks = K + ((size_t)bh * SK + kt * 64) * DHD;
  half_t* kd = khn + ((size_t)bh * SK + kt * 64) * DHD;
#pragma unroll
  for (int j = 0; j < 2; ++j) {
    int base = j * 2048 + tid * 8;
    f32x4 a = *(const f32x4*)(ks + base);
    f32x4 b = *(const f32x4*)(ks + base + 4);
    half8 h;
#pragma unroll
    for (int r = 0; r < 4; ++r) {
      h[r] = (half_t)(-a[r]);
      h[4 + r] = (half_t)(-b[r]);
    }
    *(half8*)(kd + base) = h;
  }
  __shared__ float tile[64][65];
  const float* vs = V + ((size_t)bh * SK + kt * 64) * DHD;
#pragma unroll
  for (int i = 0; i < 16; ++i) {
    int idx = i * 256 + tid;
    tile[idx >> 6][idx & 63] = vs[idx];
  }
  __syncthreads();
#pragma unroll
  for (int i = 0; i < 16; ++i) {
    int idx = i * 256 + tid;
    int d = idx >> 6, kk = idx & 63;
    vt[((size_t)bh * DHD + d) * SK + kt * 64 + kk] = (half_t)tile[kk][d];
  }
}

// ---- q projection: q = (emb @ Wq^T + bq) * 0.125 * log2(e)  (exp2-folded) ----
__global__ __launch_bounds__(256) void proj_kernel(const half_t* __restrict__ emb,
                                                   const half_t* __restrict__ wq,
                                                   const float* __restrict__ bq,
                                                   half_t* __restrict__ qh) {
  int bid = blockIdx.x;  // 1024, XCD-swizzled
  int xcd = bid & 7, jj = bid >> 3;
  int mt = xcd * 8 + (jj >> 4);
  int nt = jj & 15;
  int tid = threadIdx.x, wid = tid >> 6, lane = tid & 63;
  int lr = lane & 15, lg = lane >> 4;
  int m0 = mt * 64 + (wid >> 1) * 32;
  int n0 = nt * 64 + (wid & 1) * 32;
  f32x4 acc[2][2];
#pragma unroll
  for (int i = 0; i < 2; ++i)
#pragma unroll
    for (int j = 0; j < 2; ++j) acc[i][j] = (f32x4){0.f, 0.f, 0.f, 0.f};

  for (int kk = 0; kk < E_; kk += 32) {
    half8 a[2], b[2];
#pragma unroll
    for (int g = 0; g < 2; ++g) {
      a[g] = *(const half8*)(emb + (size_t)(m0 + g * 16 + lr) * E_ + kk + lg * 8);
      b[g] = *(const half8*)(wq + (size_t)(n0 + g * 16 + lr) * E_ + kk + lg * 8);
    }
#pragma unroll
    for (int i = 0; i < 2; ++i)
#pragma unroll
      for (int j = 0; j < 2; ++j) acc[i][j] = mfma16h(a[i], b[j], acc[i][j]);
  }
#pragma unroll
  for (int i = 0; i < 2; ++i)
#pragma unroll
    for (int j = 0; j < 2; ++j)
#pragma unroll
      for (int r = 0; r < 4; ++r) {
        int m = m0 + i * 16 + lg * 4 + r;  // row=(lane>>4)*4+r
        int n = n0 + j * 16 + lr;          // col=lane&15
        float v = (acc[i][j][r] + bq[n]) * 0.180336880f;  // 0.125 * log2(e)
        int b = m >> 10, sq = m & 1023, h = n >> 6, dd = n & 63;
        qh[((size_t)(b * H_ + h) * SQ + sq) * DHD + dd] = (half_t)v;
      }
}

// ---- fused attention: async global_load_lds M pipeline (T3/T4) ----
// p = exp(S-M) = exp2(-T)*exp(-M). eS panel via MFMA (8 waves x 128 k);
// M streamed as 4 x 256-col strips direct-to-LDS (1 KB/instr, 4 instr/wave/
// strip, double-buffered, counted vmcnt(4) -- never drained mid-loop).
// Rows padded to 264 f32 between-instruction (linear-dest rule respected).
__global__ __launch_bounds__(512, 2) void attn_kernel(const half_t* __restrict__ qh,
                                                      const half_t* __restrict__ khn,
                                                      const half_t* __restrict__ vt,
                                                      const float* __restrict__ M,
                                                      const float* __restrict__ dpm,
                                                      float* __restrict__ out,
                                                      float* __restrict__ pm) {
  __shared__ half_t panel[32][1032];  // eS then p, fp16 (+8 pad)
  __shared__ float mbuf[2][32][264];  // M strips fp32 (+8 pad between rows)
  __shared__ float rowscale[32];

  int bid = blockIdx.x;
  int x = bid & 7, j = bid >> 3;  // 2048 blocks = 8 XCD x 256
  int bh = x * 8 + (j >> 5);      // 8 bh per XCD (K/V/q L2-resident)
  int qt = j & 31;
  int q0 = qt << 5;
  int b = bh >> 4, h = bh & 15;

  int tid = threadIdx.x, wid = tid >> 6, lane = tid & 63;
  int lr = lane & 15, lg = lane >> 4;

  const float* mbase = M + ((size_t)bh * SQ + q0) * SK;

  // ---- prologue: issue strips 0,1 async (wave owns rows wid*4..+3) ----
#pragma unroll
  for (int s = 0; s < 2; ++s)
#pragma unroll
    for (int i = 0; i < 4; ++i) {
      int row = wid * 4 + i;
      const float* g = mbase + (size_t)row * SK + s * 256 + lane * 4;
      __builtin_amdgcn_global_load_lds(
          (const __attribute__((address_space(1))) void*)g,
          (__attribute__((address_space(3))) void*)&mbuf[s][row][0], 16, 0, 0);
    }

  // ---- phase A: eS = exp2(-T) panel. wave owns k in [wid*128, +128) ----
  {
    const half_t* qbase = qh + ((size_t)bh * SQ + q0) * DHD;
    half8 aq[2][2];
#pragma unroll
    for (int qg = 0; qg < 2; ++qg)
#pragma unroll
      for (int dh = 0; dh < 2; ++dh)
        aq[qg][dh] =
            *(const half8*)(qbase + (size_t)(qg * 16 + lr) * DHD + dh * 32 + lg * 8);
    int kc0 = wid * 128;
#pragma unroll
    for (int kt = 0; kt < 8; ++kt) {
      const half_t* kr = khn + ((size_t)bh * SK + kc0 + kt * 16 + lr) * DHD + lg * 8;
      half8 k0 = *(const half8*)(kr);
      half8 k1 = *(const half8*)(kr + 32);
#pragma unroll
      for (int qg = 0; qg < 2; ++qg) {
        f32x4 T = (f32x4){0.f, 0.f, 0.f, 0.f};
        T = mfma16h(k0, aq[qg][0], T);
        T = mfma16h(k1, aq[qg][1], T);
        half4 ph;
#pragma unroll
        for (int r = 0; r < 4; ++r) ph[r] = (half_t)exp2f(-T[r]);  // eS = exp(S)
        *(half4*)&panel[qg * 16 + lr][kc0 + kt * 16 + lg * 4] = ph;
      }
    }
  }

  // ---- strip loop: consume M strips, p = eS * exp(-M), rowsums ----
  int qr = tid >> 4, sub = tid & 15;
  float rsum = 0.f;
#pragma unroll
  for (int c = 0; c < 4; ++c) {
    if (c < 3)
      asm volatile("s_waitcnt vmcnt(4)" ::: "memory");  // strip c done; c+1 in flight
    else
      asm volatile("s_waitcnt vmcnt(0)" ::: "memory");
    __builtin_amdgcn_sched_barrier(0);
    lds_barrier();  // all waves' strip-c rows present (also orders panel writes)
#pragma unroll
    for (int jj = 0; jj < 4; ++jj) {
      f32x4 m = *(const f32x4*)&mbuf[c & 1][qr][sub * 4 + jj * 64];
      half4 es = *(const half4*)&panel[qr][c * 256 + sub * 4 + jj * 64];
      half4 ph;
#pragma unroll
      for (int r = 0; r < 4; ++r) {
        float p = (float)es[r] * __expf(-m[r]);
        rsum += p;
        ph[r] = (half_t)p;
      }
      *(half4*)&panel[qr][c * 256 + sub * 4 + jj * 64] = ph;
    }
    lds_barrier();  // slot c&1 fully consumed by all waves
    if (c < 2) {
#pragma unroll
      for (int i = 0; i < 4; ++i) {
        int row = wid * 4 + i;
        const float* g = mbase + (size_t)row * SK + (c + 2) * 256 + lane * 4;
        __builtin_amdgcn_global_load_lds(
            (const __attribute__((address_space(1))) void*)g,
            (__attribute__((address_space(3))) void*)&mbuf[c & 1][row][0], 16, 0, 0);
      }
    }
  }

  // row sums: full row lives in this 16-lane group
  rsum += __shfl_xor(rsum, 1);
  rsum += __shfl_xor(rsum, 2);
  rsum += __shfl_xor(rsum, 4);
  rsum += __shfl_xor(rsum, 8);
  if (sub == 0) rowscale[qr] = dpm[b * SQ + q0 + qr] / rsum;
  lds_barrier();

  // ---- phase C: PV (8 waves = 2 qg x 4 d-tiles) ----
  int qg = wid >> 2, d0 = (wid & 3) * 16;
  const half_t* vrow = vt + ((size_t)bh * DHD + d0 + lr) * SK;
  f32x4 acc = (f32x4){0.f, 0.f, 0.f, 0.f};
#pragma unroll 8
  for (int ks = 0; ks < SK; ks += 32) {
    half8 av = *(const half8*)(vrow + ks + lg * 8);
    half8 bp = *(const half8*)&panel[qg * 16 + lr][ks + lg * 8];
    acc = mfma16h(av, bp, acc);
  }
  float rs = rowscale[qg * 16 + lr];
  f32x4 res;
#pragma unroll
  for (int r = 0; r < 4; ++r) res[r] = acc[r] * rs;
  *(f32x4*)(out + ((size_t)b * SQ + q0 + qg * 16 + lr) * E_ + h * DHD + d0 + lg * 4) = res;

  // ---- colmax partial over this block's 32 q-rows -> plain coalesced store ----
  {
    int c = tid * 2;
    float m0 = 0.f, m1 = 0.f;
#pragma unroll 8
    for (int r = 0; r < 32; ++r) {
      float w = rowscale[r];
      m0 = fmaxf(m0, (float)panel[r][c] * w);
      m1 = fmaxf(m1, (float)panel[r][c + 1] * w);
    }
    float* pmrow = pm + ((size_t)bh * 32 + qt) * SK + c;
    pmrow[0] = m0;
    pmrow[1] = m1;
  }
}

// ---- target_score: out[b][k] = sum_h max_qt pm[b*16+h][qt][k] ----
__global__ __launch_bounds__(256) void tscore_kernel(const float* __restrict__ pm,
                                                     float* __restrict__ out) {
  int bb = blockIdx.x;  // 64 = 4 b x 16 k-chunks
  int b = bb >> 4, kq = bb & 15;
  int t = threadIdx.x;
  int kl = t & 63, hg = t >> 6;  // 4 h-groups x 64 k
  int k = kq * 64 + kl;
  float s = 0.f;
#pragma unroll
  for (int hh = hg * 4; hh < hg * 4 + 4; ++hh) {
    const float* p = pm + ((size_t)(b * H_ + hh) * 32) * SK + k;
    float mx = 0.f;
#pragma unroll
    for (int qt = 0; qt < 32; ++qt) mx = fmaxf(mx, p[(size_t)qt * SK]);
    s += mx;
  }
  __shared__ float red[4][64];
  red[hg][kl] = s;
  __syncthreads();
  if (t < 64)
    out[(size_t)B_ * SQ * E_ + b * SK + kq * 64 + t] =
        red[0][t] + red[1][t] + red[2][t] + red[3][t];
}

extern "C" void kernel_launch(void* const* d_in, const int* in_sizes, int n_in,
                              void* d_out, int out_size, void* d_ws, size_t ws_size,
                              hipStream_t stream) {
  const float* dp_emb = (const float*)d_in[0];
  const float* dp_mask = (const float*)d_in[1];
  const float* K = (const float*)d_in[2];
  const float* V = (const float*)d_in[3];
  const float* M = (const float*)d_in[4];
  const float* Wq = (const float*)d_in[5];
  const float* bq = (const float*)d_in[6];
  float* out = (float*)d_out;

  char* ws = (char*)d_ws;
  half_t* q_h = (half_t*)(ws);                    // 8 MB  [BH,Sq,64]
  half_t* k_hn = (half_t*)(ws + (8ull << 20));    // 8 MB  [BH,Sk,64] (negated)
  half_t* vt_h = (half_t*)(ws + (16ull << 20));   // 8 MB  [BH,64,Sk]
  half_t* emb_h = (half_t*)(ws + (24ull << 20));  // 8 MB  [B*Sq,E]
  half_t* wq_h = (half_t*)(ws + (32ull << 20));   // 2 MB  [E,E]
  float* pm = (float*)(ws + (34ull << 20));       // 8 MB  [BH,32,Sk] colmax partials

  prep_kernel<<<QW_BLOCKS + B_ * H_ * 16, 256, 0, stream>>>(dp_emb, Wq, K, V, emb_h, wq_h,
                                                            k_hn, vt_h);
  proj_kernel<<<1024, 256, 0, stream>>>(emb_h, wq_h, bq, q_h);
  attn_kernel<<<B_ * H_ * (SQ / 32), 512, 0, stream>>>(q_h, k_hn, vt_h, M, dp_mask, out, pm);
  tscore_kernel<<<64, 256, 0, stream>>>(pm, out);
}

// Round 17
// 235.149 us; speedup vs baseline: 1.0192x; 1.0192x over previous
//
#include <hip/hip_runtime.h>

#define B_ 4
#define H_ 16
#define SQ 1024
#define SK 1024
#define DHD 64
#define E_ 1024
#define LOG2E 1.44269504f

typedef _Float16 half_t;
typedef __attribute__((ext_vector_type(8))) _Float16 half8;
typedef __attribute__((ext_vector_type(4))) _Float16 half4;
typedef __attribute__((ext_vector_type(4))) float f32x4;

static __device__ __forceinline__ f32x4 mfma16h(half8 a, half8 b, f32x4 c) {
  return __builtin_amdgcn_mfma_f32_16x16x32_f16(a, b, c, 0, 0, 0);
}

// ---- fused prep: emb/Wq fp32->fp16, K -> -K fp16, V -> V^T fp16 ----
#define QW_BLOCKS 2560  // 2048 (emb) + 512 (wq)
__global__ __launch_bounds__(256) void prep_kernel(const float* __restrict__ emb,
                                                   const float* __restrict__ wq,
                                                   const float* __restrict__ K,
                                                   const float* __restrict__ V,
                                                   half_t* __restrict__ emb_h,
                                                   half_t* __restrict__ wq_h,
                                                   half_t* __restrict__ khn,
                                                   half_t* __restrict__ vt) {
  int bid = blockIdx.x, tid = threadIdx.x;
  if (bid < QW_BLOCKS) {
    int i = bid * 256 + tid;
    const float* src;
    half_t* dst;
    if (i < (B_ * SQ * E_ / 8)) {
      src = emb;
      dst = emb_h;
    } else {
      i -= B_ * SQ * E_ / 8;
      src = wq;
      dst = wq_h;
    }
    size_t off = (size_t)i * 8;
    f32x4 v0 = *(const f32x4*)(src + off);
    f32x4 v1 = *(const f32x4*)(src + off + 4);
    half8 h;
#pragma unroll
    for (int j = 0; j < 4; ++j) {
      h[j] = (half_t)v0[j];
      h[4 + j] = (half_t)v1[j];
    }
    *(half8*)(dst + off) = h;
    return;
  }
  bid -= QW_BLOCKS;  // 1024 kv blocks
  int bh = bid >> 4, kt = bid & 15;
  const float* ks = K + ((size_t)bh * SK + kt * 64) * DHD;
  half_t* kd = khn + ((size_t)bh * SK + kt * 64) * DHD;
#pragma unroll
  for (int j = 0; j < 2; ++j) {
    int base = j * 2048 + tid * 8;
    f32x4 a = *(const f32x4*)(ks + base);
    f32x4 b = *(const f32x4*)(ks + base + 4);
    half8 h;
#pragma unroll
    for (int r = 0; r < 4; ++r) {
      h[r] = (half_t)(-a[r]);
      h[4 + r] = (half_t)(-b[r]);
    }
    *(half8*)(kd + base) = h;
  }
  __shared__ float tile[64][65];
  const float* vs = V + ((size_t)bh * SK + kt * 64) * DHD;
#pragma unroll
  for (int i = 0; i < 16; ++i) {
    int idx = i * 256 + tid;
    tile[idx >> 6][idx & 63] = vs[idx];
  }
  __syncthreads();
#pragma unroll
  for (int i = 0; i < 16; ++i) {
    int idx = i * 256 + tid;
    int d = idx >> 6, kk = idx & 63;
    vt[((size_t)bh * DHD + d) * SK + kt * 64 + kk] = (half_t)tile[kk][d];
  }
}

// ---- q projection: q = (emb @ Wq^T + bq) * 0.125 * log2(e)  (exp2-folded) ----
__global__ __launch_bounds__(256) void proj_kernel(const half_t* __restrict__ emb,
                                                   const half_t* __restrict__ wq,
                                                   const float* __restrict__ bq,
                                                   half_t* __restrict__ qh) {
  int bid = blockIdx.x;  // 1024, XCD-swizzled
  int xcd = bid & 7, jj = bid >> 3;
  int mt = xcd * 8 + (jj >> 4);
  int nt = jj & 15;
  int tid = threadIdx.x, wid = tid >> 6, lane = tid & 63;
  int lr = lane & 15, lg = lane >> 4;
  int m0 = mt * 64 + (wid >> 1) * 32;
  int n0 = nt * 64 + (wid & 1) * 32;
  f32x4 acc[2][2];
#pragma unroll
  for (int i = 0; i < 2; ++i)
#pragma unroll
    for (int j = 0; j < 2; ++j) acc[i][j] = (f32x4){0.f, 0.f, 0.f, 0.f};

  for (int kk = 0; kk < E_; kk += 32) {
    half8 a[2], b[2];
#pragma unroll
    for (int g = 0; g < 2; ++g) {
      a[g] = *(const half8*)(emb + (size_t)(m0 + g * 16 + lr) * E_ + kk + lg * 8);
      b[g] = *(const half8*)(wq + (size_t)(n0 + g * 16 + lr) * E_ + kk + lg * 8);
    }
#pragma unroll
    for (int i = 0; i < 2; ++i)
#pragma unroll
      for (int j = 0; j < 2; ++j) acc[i][j] = mfma16h(a[i], b[j], acc[i][j]);
  }
#pragma unroll
  for (int i = 0; i < 2; ++i)
#pragma unroll
    for (int j = 0; j < 2; ++j)
#pragma unroll
      for (int r = 0; r < 4; ++r) {
        int m = m0 + i * 16 + lg * 4 + r;  // row=(lane>>4)*4+r
        int n = n0 + j * 16 + lr;          // col=lane&15
        float v = (acc[i][j][r] + bq[n]) * (0.125f * LOG2E);
        int b = m >> 10, sq = m & 1023, h = n >> 6, dd = n & 63;
        qh[((size_t)(b * H_ + h) * SQ + sq) * DHD + dd] = (half_t)v;
      }
}

// ---- fused attention: dense-stream phase 0 + single-exp2 softmax ----
// p = exp(S - M) = exp2(-T - ml), T = K~.q' (khn=-K, q'=q*0.125*log2e),
// ml = M*log2e (fp16, staged in panel by a PURE streaming phase: all 512
// threads issue only coalesced f32x4 M loads, 8 deep). 16-row q-tiles,
// 33 KB LDS -> 3-4 blocks/CU so co-resident blocks fill each other's
// HBM gaps. Post-barrier: waves 0-3 PV MFMA, waves 4-7 colmax, concurrent.
__global__ __launch_bounds__(512, 6) void attn_kernel(const half_t* __restrict__ qh,
                                                      const half_t* __restrict__ khn,
                                                      const half_t* __restrict__ vt,
                                                      const float* __restrict__ M,
                                                      const float* __restrict__ dpm,
                                                      float* __restrict__ out,
                                                      float* __restrict__ pm) {
  __shared__ half_t panel[16][1032];  // ml then p, fp16 (+8 pad)
  __shared__ float wred[8][16];
  __shared__ float rowscale[16];

  int bid = blockIdx.x;
  int x = bid & 7, j = bid >> 3;  // 4096 blocks = 8 XCD x 512
  int bh = x * 8 + (j >> 6);      // 8 bh per XCD (K/V/q L2-resident)
  int qt = j & 63;                // 64 q-tiles of 16 rows
  int q0 = qt << 4;
  int b = bh >> 4, h = bh & 15;

  int tid = threadIdx.x, wid = tid >> 6, lane = tid & 63;
  int lr = lane & 15, lg = lane >> 4;

  // ---- phase 0: pure M stream -> ml = M*log2e fp16 panel ----
  // thread t: row t>>5, cols (t&31)*4 + 128j. Per wave-instr: 2x512B contig.
  {
    int row = tid >> 5, cb = (tid & 31) * 4;
    const float* mr = M + ((size_t)bh * SQ + q0 + row) * SK + cb;
    f32x4 mv[8];
#pragma unroll
    for (int jj = 0; jj < 8; ++jj) mv[jj] = *(const f32x4*)(mr + jj * 128);
#pragma unroll
    for (int jj = 0; jj < 8; ++jj) {
      half4 e;
#pragma unroll
      for (int r = 0; r < 4; ++r) e[r] = (half_t)(mv[jj][r] * LOG2E);
      *(half4*)&panel[row][cb + jj * 128] = e;
    }
  }
  __syncthreads();

  // ---- phase 1: T = K~.q' MFMA; p = exp2(-T - ml); in-place panel update ----
  float rsum = 0.f;
  {
    const half_t* qbase = qh + ((size_t)bh * SQ + q0) * DHD;
    half8 aq0 = *(const half8*)(qbase + (size_t)lr * DHD + lg * 8);
    half8 aq1 = *(const half8*)(qbase + (size_t)lr * DHD + 32 + lg * 8);
    int kc0 = wid * 128;
#pragma unroll
    for (int kt = 0; kt < 8; ++kt) {
      const half_t* kr = khn + ((size_t)bh * SK + kc0 + kt * 16 + lr) * DHD + lg * 8;
      half8 k0 = *(const half8*)(kr);
      half8 k1 = *(const half8*)(kr + 32);
      f32x4 T = (f32x4){0.f, 0.f, 0.f, 0.f};
      T = mfma16h(k0, aq0, T);
      T = mfma16h(k1, aq1, T);
      half4 ml = *(const half4*)&panel[lr][kc0 + kt * 16 + lg * 4];
      half4 ph;
#pragma unroll
      for (int r = 0; r < 4; ++r) {
        float p = exp2f(-T[r] - (float)ml[r]);  // p = exp(S - M), bounded
        rsum += p;
        ph[r] = (half_t)p;
      }
      *(half4*)&panel[lr][kc0 + kt * 16 + lg * 4] = ph;
    }
  }
  // partial row sums (row = lr): reduce over lg groups, combine across waves
  rsum += __shfl_xor(rsum, 16);
  rsum += __shfl_xor(rsum, 32);
  if (lg == 0) wred[wid][lr] = rsum;
  __syncthreads();
  if (tid < 16) {
    float s = 0.f;
#pragma unroll
    for (int w = 0; w < 8; ++w) s += wred[w][tid];
    rowscale[tid] = dpm[b * SQ + q0 + tid] / s;
  }
  __syncthreads();

  if (wid < 4) {
    // ---- PV: 4 waves = 4 d-tiles of 16; full k ----
    int d0 = wid * 16;
    const half_t* vrow = vt + ((size_t)bh * DHD + d0 + lr) * SK;
    f32x4 acc = (f32x4){0.f, 0.f, 0.f, 0.f};
#pragma unroll 8
    for (int ks = 0; ks < SK; ks += 32) {
      half8 av = *(const half8*)(vrow + ks + lg * 8);
      half8 bp = *(const half8*)&panel[lr][ks + lg * 8];
      acc = mfma16h(av, bp, acc);
    }
    float rs = rowscale[lr];
    f32x4 res;
#pragma unroll
    for (int r = 0; r < 4; ++r) res[r] = acc[r] * rs;
    *(f32x4*)(out + ((size_t)b * SQ + q0 + lr) * E_ + h * DHD + d0 + lg * 4) = res;
  } else {
    // ---- colmax over the 16 q-rows -> plain coalesced f32x4 store ----
    int c0 = ((wid - 4) * 64 + lane) * 4;  // 256 threads x 4 cols
    f32x4 cm = (f32x4){0.f, 0.f, 0.f, 0.f};
#pragma unroll
    for (int r = 0; r < 16; ++r) {
      half4 ph = *(const half4*)&panel[r][c0];
      float w = rowscale[r];
#pragma unroll
      for (int i = 0; i < 4; ++i) cm[i] = fmaxf(cm[i], (float)ph[i] * w);
    }
    *(f32x4*)(pm + ((size_t)bh * 64 + qt) * SK + c0) = cm;
  }
}

// ---- target_score: out[b][k] = sum_h max_qt pm[bh][qt][k] ----
__global__ __launch_bounds__(256) void tscore_kernel(const float* __restrict__ pm,
                                                     float* __restrict__ out) {
  int bb = blockIdx.x;  // 64 = 4 b x 16 k-chunks
  int b = bb >> 4, kq = bb & 15;
  int t = threadIdx.x;
  int kl = t & 63, hg = t >> 6;  // 4 h-groups x 64 k
  int k = kq * 64 + kl;
  float s = 0.f;
#pragma unroll
  for (int hh = hg * 4; hh < hg * 4 + 4; ++hh) {
    const float* p = pm + ((size_t)(b * H_ + hh) * 64) * SK + k;
    float mx = 0.f;
#pragma unroll
    for (int qt = 0; qt < 64; ++qt) mx = fmaxf(mx, p[(size_t)qt * SK]);
    s += mx;
  }
  __shared__ float red[4][64];
  red[hg][kl] = s;
  __syncthreads();
  if (t < 64)
    out[(size_t)B_ * SQ * E_ + b * SK + kq * 64 + t] =
        red[0][t] + red[1][t] + red[2][t] + red[3][t];
}

extern "C" void kernel_launch(void* const* d_in, const int* in_sizes, int n_in,
                              void* d_out, int out_size, void* d_ws, size_t ws_size,
                              hipStream_t stream) {
  const float* dp_emb = (const float*)d_in[0];
  const float* dp_mask = (const float*)d_in[1];
  const float* K = (const float*)d_in[2];
  const float* V = (const float*)d_in[3];
  const float* M = (const float*)d_in[4];
  const float* Wq = (const float*)d_in[5];
  const float* bq = (const float*)d_in[6];
  float* out = (float*)d_out;

  char* ws = (char*)d_ws;
  half_t* q_h = (half_t*)(ws);                    // 8 MB  [BH,Sq,64]
  half_t* k_hn = (half_t*)(ws + (8ull << 20));    // 8 MB  [BH,Sk,64] (negated)
  half_t* vt_h = (half_t*)(ws + (16ull << 20));   // 8 MB  [BH,64,Sk]
  half_t* emb_h = (half_t*)(ws + (24ull << 20));  // 8 MB  [B*Sq,E]
  half_t* wq_h = (half_t*)(ws + (32ull << 20));   // 2 MB  [E,E]
  float* pm = (float*)(ws + (34ull << 20));       // 16 MB [BH,64,Sk] colmax partials

  prep_kernel<<<QW_BLOCKS + B_ * H_ * 16, 256, 0, stream>>>(dp_emb, Wq, K, V, emb_h, wq_h,
                                                            k_hn, vt_h);
  proj_kernel<<<1024, 256, 0, stream>>>(emb_h, wq_h, bq, q_h);
  attn_kernel<<<B_ * H_ * (SQ / 16), 512, 0, stream>>>(q_h, k_hn, vt_h, M, dp_mask, out, pm);
  tscore_kernel<<<64, 256, 0, stream>>>(pm, out);
}

// Round 18
// 208.427 us; speedup vs baseline: 1.1498x; 1.1282x over previous
//
#include <hip/hip_runtime.h>

#define B_ 4
#define H_ 16
#define SQ 1024
#define SK 1024
#define DHD 64
#define E_ 1024

typedef _Float16 half_t;
typedef __attribute__((ext_vector_type(8))) _Float16 half8;
typedef __attribute__((ext_vector_type(4))) _Float16 half4;
typedef __attribute__((ext_vector_type(4))) float f32x4;

static __device__ __forceinline__ f32x4 mfma16h(half8 a, half8 b, f32x4 c) {
  return __builtin_amdgcn_mfma_f32_16x16x32_f16(a, b, c, 0, 0, 0);
}
// LDS-only barrier: do NOT drain vmcnt (keeps the upfront M loads in flight;
// __syncthreads would emit s_waitcnt vmcnt(0) and kill the prefetch)
static __device__ __forceinline__ void lds_barrier() {
  asm volatile("s_waitcnt lgkmcnt(0)" ::: "memory");
  __builtin_amdgcn_s_barrier();
}

// ---- fused prep: emb/Wq fp32->fp16, K -> -K fp16, V -> V^T fp16 ----
#define QW_BLOCKS 2560  // 2048 (emb) + 512 (wq)
__global__ __launch_bounds__(256) void prep_kernel(const float* __restrict__ emb,
                                                   const float* __restrict__ wq,
                                                   const float* __restrict__ K,
                                                   const float* __restrict__ V,
                                                   half_t* __restrict__ emb_h,
                                                   half_t* __restrict__ wq_h,
                                                   half_t* __restrict__ khn,
                                                   half_t* __restrict__ vt) {
  int bid = blockIdx.x, tid = threadIdx.x;
  if (bid < QW_BLOCKS) {
    int i = bid * 256 + tid;
    const float* src;
    half_t* dst;
    if (i < (B_ * SQ * E_ / 8)) {
      src = emb;
      dst = emb_h;
    } else {
      i -= B_ * SQ * E_ / 8;
      src = wq;
      dst = wq_h;
    }
    size_t off = (size_t)i * 8;
    f32x4 v0 = *(const f32x4*)(src + off);
    f32x4 v1 = *(const f32x4*)(src + off + 4);
    half8 h;
#pragma unroll
    for (int j = 0; j < 4; ++j) {
      h[j] = (half_t)v0[j];
      h[4 + j] = (half_t)v1[j];
    }
    *(half8*)(dst + off) = h;
    return;
  }
  bid -= QW_BLOCKS;  // 1024 kv blocks
  int bh = bid >> 4, kt = bid & 15;
  const float* ks = K + ((size_t)bh * SK + kt * 64) * DHD;
  half_t* kd = khn + ((size_t)bh * SK + kt * 64) * DHD;
#pragma unroll
  for (int j = 0; j < 2; ++j) {
    int base = j * 2048 + tid * 8;
    f32x4 a = *(const f32x4*)(ks + base);
    f32x4 b = *(const f32x4*)(ks + base + 4);
    half8 h;
#pragma unroll
    for (int r = 0; r < 4; ++r) {
      h[r] = (half_t)(-a[r]);
      h[4 + r] = (half_t)(-b[r]);
    }
    *(half8*)(kd + base) = h;
  }
  __shared__ float tile[64][65];
  const float* vs = V + ((size_t)bh * SK + kt * 64) * DHD;
#pragma unroll
  for (int i = 0; i < 16; ++i) {
    int idx = i * 256 + tid;
    tile[idx >> 6][idx & 63] = vs[idx];
  }
  __syncthreads();
#pragma unroll
  for (int i = 0; i < 16; ++i) {
    int idx = i * 256 + tid;
    int d = idx >> 6, kk = idx & 63;
    vt[((size_t)bh * DHD + d) * SK + kt * 64 + kk] = (half_t)tile[kk][d];
  }
}

// ---- q projection: q = (emb @ Wq^T + bq) * 0.125 * log2(e)  (exp2-folded) ----
__global__ __launch_bounds__(256) void proj_kernel(const half_t* __restrict__ emb,
                                                   const half_t* __restrict__ wq,
                                                   const float* __restrict__ bq,
                                                   half_t* __restrict__ qh) {
  int bid = blockIdx.x;  // 1024, XCD-swizzled
  int xcd = bid & 7, jj = bid >> 3;
  int mt = xcd * 8 + (jj >> 4);
  int nt = jj & 15;
  int tid = threadIdx.x, wid = tid >> 6, lane = tid & 63;
  int lr = lane & 15, lg = lane >> 4;
  int m0 = mt * 64 + (wid >> 1) * 32;
  int n0 = nt * 64 + (wid & 1) * 32;
  f32x4 acc[2][2];
#pragma unroll
  for (int i = 0; i < 2; ++i)
#pragma unroll
    for (int j = 0; j < 2; ++j) acc[i][j] = (f32x4){0.f, 0.f, 0.f, 0.f};

  for (int kk = 0; kk < E_; kk += 32) {
    half8 a[2], b[2];
#pragma unroll
    for (int g = 0; g < 2; ++g) {
      a[g] = *(const half8*)(emb + (size_t)(m0 + g * 16 + lr) * E_ + kk + lg * 8);
      b[g] = *(const half8*)(wq + (size_t)(n0 + g * 16 + lr) * E_ + kk + lg * 8);
    }
#pragma unroll
    for (int i = 0; i < 2; ++i)
#pragma unroll
      for (int j = 0; j < 2; ++j) acc[i][j] = mfma16h(a[i], b[j], acc[i][j]);
  }
#pragma unroll
  for (int i = 0; i < 2; ++i)
#pragma unroll
    for (int j = 0; j < 2; ++j)
#pragma unroll
      for (int r = 0; r < 4; ++r) {
        int m = m0 + i * 16 + lg * 4 + r;  // row=(lane>>4)*4+r
        int n = n0 + j * 16 + lr;          // col=lane&15
        float v = (acc[i][j][r] + bq[n]) * 0.180336880f;  // 0.125 * log2(e)
        int b = m >> 10, sq = m & 1023, h = n >> 6, dd = n & 63;
        qh[((size_t)(b * H_ + h) * SQ + sq) * DHD + dd] = (half_t)v;
      }
}

// ---- fused attention: upfront NONTEMPORAL M-prefetch, exp-factored softmax ----
// p = exp(S-M) = exp2(-T)*exp(-M), T = K~.q' (khn=-K, q'=q*0.125*log2e).
// M is read with nt loads (no L2/L3 allocation): M thrashes the 256MB L3
// otherwise, and the mixed L3-hit/HBM-miss path was pinned at ~1.5 TB/s
// across r2..r17 regardless of kernel structure. nt -> pure HBM stream,
// and K/V/q stay L3-resident instead of being evicted by M.
__global__ __launch_bounds__(512, 4) void attn_kernel(const half_t* __restrict__ qh,
                                                      const half_t* __restrict__ khn,
                                                      const half_t* __restrict__ vt,
                                                      const float* __restrict__ M,
                                                      const float* __restrict__ dpm,
                                                      float* __restrict__ out,
                                                      float* __restrict__ pm) {
  __shared__ half_t panel[32][1032];  // eS then p, fp16 (+8 pad)
  __shared__ float rowscale[32];

  int bid = blockIdx.x;
  int x = bid & 7, j = bid >> 3;  // 2048 blocks = 8 XCD x 256
  int bh = x * 8 + (j >> 5);      // 8 bh per XCD (K/V/q L2-resident)
  int qt = j & 31;
  int q0 = qt << 5;
  int b = bh >> 4, h = bh & 15;

  int tid = threadIdx.x, wid = tid >> 6, lane = tid & 63;
  int lr = lane & 15, lg = lane >> 4;

  // ---- upfront M prefetch (nontemporal): row qr = wid*4+lg, 16 lanes/row ----
  int qr = wid * 4 + lg;
  const float* mrow = M + ((size_t)bh * SQ + q0 + qr) * SK + lr * 4;
  f32x4 ms[16];
#pragma unroll
  for (int i = 0; i < 16; ++i)
    ms[i] = __builtin_nontemporal_load((const f32x4*)(mrow + i * 64));
  __builtin_amdgcn_sched_barrier(0);  // pin: loads must not sink below here

  // q fragments (A-mapping)
  const half_t* qbase = qh + ((size_t)bh * SQ + q0) * DHD;
  half8 aq[2][2];
#pragma unroll
  for (int qg = 0; qg < 2; ++qg)
#pragma unroll
    for (int dh = 0; dh < 2; ++dh)
      aq[qg][dh] = *(const half8*)(qbase + (size_t)(qg * 16 + lr) * DHD + dh * 32 + lg * 8);

  // ---- phase A: eS = exp2(-T) panel. wave owns k in [wid*128, +128) ----
  int kc0 = wid * 128;
#pragma unroll
  for (int kt = 0; kt < 8; ++kt) {
    const half_t* kr = khn + ((size_t)bh * SK + kc0 + kt * 16 + lr) * DHD + lg * 8;
    half8 k0 = *(const half8*)(kr);
    half8 k1 = *(const half8*)(kr + 32);
#pragma unroll
    for (int qg = 0; qg < 2; ++qg) {
      f32x4 T = (f32x4){0.f, 0.f, 0.f, 0.f};
      T = mfma16h(k0, aq[qg][0], T);
      T = mfma16h(k1, aq[qg][1], T);
      half4 ph;
#pragma unroll
      for (int r = 0; r < 4; ++r) ph[r] = (half_t)exp2f(-T[r]);  // eS = exp(S)
      *(half4*)&panel[qg * 16 + lr][kc0 + kt * 16 + lg * 4] = ph;
    }
  }
  lds_barrier();  // panel visible; M loads still in flight until first ms use

  // ---- phase B: p = eS * exp(-M) from prefetched regs; in-register row sums ----
  half_t* prow = &panel[qr][lr * 4];
  float rsum = 0.f;
#pragma unroll
  for (int i = 0; i < 16; ++i) {
    f32x4 m = ms[i];
    half4 es = *(const half4*)(prow + i * 64);
    half4 ph;
#pragma unroll
    for (int r = 0; r < 4; ++r) {
      float p = (float)es[r] * __expf(-m[r]);
      rsum += p;
      ph[r] = (half_t)p;
    }
    *(half4*)(prow + i * 64) = ph;
  }
  rsum += __shfl_xor(rsum, 1);
  rsum += __shfl_xor(rsum, 2);
  rsum += __shfl_xor(rsum, 4);
  rsum += __shfl_xor(rsum, 8);
  if (lr == 0) rowscale[qr] = dpm[b * SQ + q0 + qr] / rsum;
  lds_barrier();

  // ---- phase C: PV (8 waves = 2 qg x 4 d-tiles) ----
  int qg = wid >> 2, d0 = (wid & 3) * 16;
  const half_t* vrow = vt + ((size_t)bh * DHD + d0 + lr) * SK;
  f32x4 acc = (f32x4){0.f, 0.f, 0.f, 0.f};
#pragma unroll 8
  for (int ks = 0; ks < SK; ks += 32) {
    half8 av = *(const half8*)(vrow + ks + lg * 8);
    half8 bp = *(const half8*)&panel[qg * 16 + lr][ks + lg * 8];
    acc = mfma16h(av, bp, acc);
  }
  float rs = rowscale[qg * 16 + lr];
  f32x4 res;
#pragma unroll
  for (int r = 0; r < 4; ++r) res[r] = acc[r] * rs;
  *(f32x4*)(out + ((size_t)b * SQ + q0 + qg * 16 + lr) * E_ + h * DHD + d0 + lg * 4) = res;

  // ---- colmax partial over this block's 32 q-rows -> plain coalesced store ----
  {
    int c = tid * 2;
    float m0 = 0.f, m1 = 0.f;
#pragma unroll 8
    for (int r = 0; r < 32; ++r) {
      float w = rowscale[r];
      m0 = fmaxf(m0, (float)panel[r][c] * w);
      m1 = fmaxf(m1, (float)panel[r][c + 1] * w);
    }
    float* pmrow = pm + ((size_t)bh * 32 + qt) * SK + c;
    pmrow[0] = m0;
    pmrow[1] = m1;
  }
}

// ---- target_score: out[b][k] = sum_h max_qt pm[b*16+h][qt][k] ----
__global__ __launch_bounds__(256) void tscore_kernel(const float* __restrict__ pm,
                                                     float* __restrict__ out) {
  int bb = blockIdx.x;  // 64 = 4 b x 16 k-chunks
  int b = bb >> 4, kq = bb & 15;
  int t = threadIdx.x;
  int kl = t & 63, hg = t >> 6;  // 4 h-groups x 64 k
  int k = kq * 64 + kl;
  float s = 0.f;
#pragma unroll
  for (int hh = hg * 4; hh < hg * 4 + 4; ++hh) {
    const float* p = pm + ((size_t)(b * H_ + hh) * 32) * SK + k;
    float mx = 0.f;
#pragma unroll
    for (int qt = 0; qt < 32; ++qt) mx = fmaxf(mx, p[(size_t)qt * SK]);
    s += mx;
  }
  __shared__ float red[4][64];
  red[hg][kl] = s;
  __syncthreads();
  if (t < 64)
    out[(size_t)B_ * SQ * E_ + b * SK + kq * 64 + t] =
        red[0][t] + red[1][t] + red[2][t] + red[3][t];
}

extern "C" void kernel_launch(void* const* d_in, const int* in_sizes, int n_in,
                              void* d_out, int out_size, void* d_ws, size_t ws_size,
                              hipStream_t stream) {
  const float* dp_emb = (const float*)d_in[0];
  const float* dp_mask = (const float*)d_in[1];
  const float* K = (const float*)d_in[2];
  const float* V = (const float*)d_in[3];
  const float* M = (const float*)d_in[4];
  const float* Wq = (const float*)d_in[5];
  const float* bq = (const float*)d_in[6];
  float* out = (float*)d_out;

  char* ws = (char*)d_ws;
  half_t* q_h = (half_t*)(ws);                    // 8 MB  [BH,Sq,64]
  half_t* k_hn = (half_t*)(ws + (8ull << 20));    // 8 MB  [BH,Sk,64] (negated)
  half_t* vt_h = (half_t*)(ws + (16ull << 20));   // 8 MB  [BH,64,Sk]
  half_t* emb_h = (half_t*)(ws + (24ull << 20));  // 8 MB  [B*Sq,E]
  half_t* wq_h = (half_t*)(ws + (32ull << 20));   // 2 MB  [E,E]
  float* pm = (float*)(ws + (34ull << 20));       // 8 MB  [BH,32,Sk] colmax partials

  prep_kernel<<<QW_BLOCKS + B_ * H_ * 16, 256, 0, stream>>>(dp_emb, Wq, K, V, emb_h, wq_h,
                                                            k_hn, vt_h);
  proj_kernel<<<1024, 256, 0, stream>>>(emb_h, wq_h, bq, q_h);
  attn_kernel<<<B_ * H_ * (SQ / 32), 512, 0, stream>>>(q_h, k_hn, vt_h, M, dp_mask, out, pm);
  tscore_kernel<<<64, 256, 0, stream>>>(pm, out);
}